// Round 9
// baseline (371.692 us; speedup 1.0000x reference)
//
#include <hip/hip_runtime.h>
#include <math.h>

#define BATCH 128
#define NPRI  32768
#define NOBJ  20
#define THRSH 0.5f
#define VARNC 0.1f

// ---- workspace layout (~37 MB) ----
#define OFF_ACC   0                      // 3 doubles
#define OFF_DONE  48                     // int
#define OFF_NPOS  64                     // 128 ints
#define OFF_BPK   2048                   // 2560 ull (zeroed by kScan; filled via atomicMax)
#define OFF_HIST  32768                  // 128*1024 uint = 512 KB (zeroed by kMatch)
#define OFF_MATCH (1 << 20)              // 16 MB u32: (iou_bits & ~31) | best_truth_idx
#define OFF_LCPP  (17 << 20)             // 16 MB float
// sort scratch ALIASES lcpp head (dead before kB writes lcpp):
#define OFF_SP    (17 << 20)             // 512 KB float4 sorted priors
#define OFF_SIDX  ((17 << 20) + (512 << 10))  // 128 KB u32 orig idx
#define OFF_CELLO ((17 << 20) + (640 << 10))  // 1 KB u32 cell offsets
#define OFF_HISTS ((17 << 20) + (644 << 10))  // 16 KB u32: 16 private 256-cell slices
#define OFF_CONF  (33 << 20)             // 4 MB bytes
#define HDR_WORDS 6144                   // 24576 B header zeroed by kScan

__device__ __forceinline__ float sl1(float d) {
    d = fabsf(d);
    return (d < 1.0f) ? 0.5f * d * d : d - 0.5f;
}
__device__ __forceinline__ float bce1(float x, bool hot) {
    float tgt = hot ? 0.925f : 0.025f;
    return fmaxf(x, 0.0f) - x * tgt + log1pf(expf(-fabsf(x)));
}
// 16x16 Morton cell from prior center (spatial locality for consecutive sorted ids)
__device__ __forceinline__ unsigned mortonCell(float cx, float cy) {
    int ix = (int)(cx * 16.0f); ix = min(max(ix, 0), 15);
    int iy = (int)(cy * 16.0f); iy = min(max(iy, 0), 15);
    return (unsigned)((ix & 1) | ((iy & 1) << 1) | ((ix & 2) << 1) | ((iy & 2) << 2)
                    | ((ix & 4) << 2) | ((iy & 4) << 3) | ((ix & 8) << 3) | ((iy & 8) << 4));
}

// ---- kHist: per-block PRIVATE 256-cell slices (no global atomics, no pre-zero) ----
__global__ __launch_bounds__(256) void kHist(const float4* __restrict__ priors,
                                             unsigned* __restrict__ histS) {
    __shared__ unsigned lc[256];
    lc[threadIdx.x] = 0;
    __syncthreads();
    const int i0 = blockIdx.x * 2048 + threadIdx.x;
    for (int j = 0; j < 8; ++j) {
        const float4 p = priors[i0 + j * 256];
        atomicAdd(&lc[mortonCell(p.x, p.y)], 1u);
    }
    __syncthreads();
    histS[blockIdx.x * 256 + threadIdx.x] = lc[threadIdx.x];   // own slice: plain store
}

// ---- kScan: sum 16 slices + exclusive scan of 256 cells; ALSO zeroes the header
// (acc/done/npos/bpk) -- replaces the hipMemsetAsync dispatch. ----
__global__ __launch_bounds__(256) void kScan(const unsigned* __restrict__ histS,
                                             unsigned* __restrict__ cellOff,
                                             unsigned* __restrict__ hdr) {
    const int tid = threadIdx.x, lane = tid & 63, w = tid >> 6;
    for (int k = tid; k < HDR_WORDS; k += 256) hdr[k] = 0;
    unsigned s = 0;
    #pragma unroll
    for (int k = 0; k < 16; ++k) s += histS[k * 256 + tid];
    unsigned inc = s;
    #pragma unroll
    for (int d = 1; d < 64; d <<= 1) { const unsigned t = __shfl_up(inc, d, 64); if (lane >= d) inc += t; }
    __shared__ unsigned wt[4];
    if (lane == 63) wt[w] = inc;
    __syncthreads();
    unsigned woff = 0;
    #pragma unroll
    for (int q = 0; q < 4; ++q) if (q < w) woff += wt[q];
    cellOff[tid] = woff + inc - s;                        // exclusive offset
}

// ---- kScat: counting-sort scatter. Order within a cell is nondeterministic but
// results are order-invariant: all argmax keys use ORIGINAL prior indices. ----
__global__ __launch_bounds__(256) void kScat(const float4* __restrict__ priors,
                                             unsigned* __restrict__ cellOff,
                                             float4* __restrict__ sp,
                                             unsigned* __restrict__ sidx) {
    const int i0 = blockIdx.x * 2048 + threadIdx.x;
    for (int j = 0; j < 8; ++j) {
        const int i = i0 + j * 256;
        const float4 p = priors[i];
        const unsigned pos = atomicAdd(&cellOff[mortonCell(p.x, p.y)], 1u);
        sp[pos] = p; sidx[pos] = (unsigned)i;
    }
}

// ---- kMatch (broad-phase): each wave owns 512 spatially-contiguous sorted priors.
// Per truth: wave-bbox reject skips the IoU body (~90% of tests). One IoU pass
// feeds BOTH argmax chains; per-prior results scatter to original indices. ----
__global__ __launch_bounds__(256) void kMatch(const float* __restrict__ targets,
                                              const float4* __restrict__ sp,
                                              const unsigned* __restrict__ sidx,
                                              unsigned long long* __restrict__ bpk,
                                              unsigned* __restrict__ match,
                                              unsigned* __restrict__ hist) {
    const int b = blockIdx.y, tid = threadIdx.x, lane = tid & 63, w = tid >> 6;
    const float* tb = targets + b * NOBJ * 6;            // block-uniform -> s_loads
    const int xb = blockIdx.x;                           // 0..15
    if (tid < 64) hist[b * 1024 + xb * 64 + tid] = 0;    // re-zero hist every launch
    const int wbase = xb * 2048 + w * 512;

    float px0[8], py0[8], px1[8], py1[8], ab[8]; unsigned op[8];
    #pragma unroll
    for (int it = 0; it < 8; ++it) {
        const int si = wbase + it * 64 + lane;           // coalesced within wave
        const float4 pr = sp[si];
        op[it] = sidx[si];
        px0[it] = pr.x - pr.z * 0.5f; py0[it] = pr.y - pr.w * 0.5f;
        px1[it] = pr.x + pr.z * 0.5f; py1[it] = pr.y + pr.w * 0.5f;
        ab[it] = (px1[it] - px0[it]) * (py1[it] - py0[it]);
    }
    // wave bbox (identical in all lanes after butterfly)
    float bx0 = px0[0], by0 = py0[0], bx1 = px1[0], by1 = py1[0];
    #pragma unroll
    for (int it = 1; it < 8; ++it) {
        bx0 = fminf(bx0, px0[it]); by0 = fminf(by0, py0[it]);
        bx1 = fmaxf(bx1, px1[it]); by1 = fmaxf(by1, py1[it]);
    }
    #pragma unroll
    for (int s = 32; s > 0; s >>= 1) {
        bx0 = fminf(bx0, __shfl_xor(bx0, s, 64)); by0 = fminf(by0, __shfl_xor(by0, s, 64));
        bx1 = fmaxf(bx1, __shfl_xor(bx1, s, 64)); by1 = fmaxf(by1, __shfl_xor(by1, s, 64));
    }
    // neutral init == (iou 0, truth 0): exactly reference's all-zero-row argmax
    float ppi[8], ppd[8]; int ppt[8];
    #pragma unroll
    for (int it = 0; it < 8; ++it) { ppi[it] = 0.0f; ppd[it] = 1.0f; ppt[it] = 0; }

    __shared__ unsigned long long red[NOBJ];
    if (tid < NOBJ) red[tid] = 0ull;
    __syncthreads();

    #pragma unroll 1
    for (int o = 0; o < NOBJ; ++o) {
        const float t0 = tb[o * 6], t1 = tb[o * 6 + 1], t2 = tb[o * 6 + 2], t3 = tb[o * 6 + 3];
        // conservative reject: bbox disjoint -> all inter==0 -> no chain update possible
        if (t2 > bx0 && t3 > by0 && t0 < bx1 && t1 < by1) {
            const float aa = (t2 - t0) * (t3 - t1);
            float tbi = -1.0f, tbd = 1.0f; int tbp = 0;
            #pragma unroll
            for (int it = 0; it < 8; ++it) {
                float ix = fminf(t2, px1[it]) - fmaxf(t0, px0[it]); ix = fmaxf(ix, 0.0f);
                float iy = fminf(t3, py1[it]) - fmaxf(t1, py0[it]); iy = fmaxf(iy, 0.0f);
                const float inter = ix * iy;
                const float den = aa + ab[it] - inter;
                // per-prior best (argmax over truths; strict > keeps first o on tie)
                if (inter * ppd[it] > ppi[it] * den) { ppi[it] = inter; ppd[it] = den; ppt[it] = o; }
                // per-truth best (fires at it=0: inter>=0 > -den)
                if (inter * tbd > tbi * den) { tbi = inter; tbd = den; tbp = (int)op[it]; }
            }
            const float iou = tbi / tbd;                 // exact div: same ordering as reference
            unsigned long long key = ((unsigned long long)__float_as_uint(iou) << 32)
                                   | (unsigned long long)(0xFFFFFFFFu - (unsigned)tbp);
            #pragma unroll
            for (int s = 32; s > 0; s >>= 1) {
                unsigned long long k2 = __shfl_xor(key, s, 64);
                if (k2 > key) key = k2;
            }
            if (lane == 0) atomicMax(&red[o], key);
        }
    }
    __syncthreads();
    if (tid < NOBJ && red[tid]) atomicMax(&bpk[b * NOBJ + tid], red[tid]);

    #pragma unroll
    for (int it = 0; it < 8; ++it) {
        const float iou = ppi[it] / ppd[it];             // same div order as reference
        match[(size_t)b * NPRI + op[it]] =               // scatter: 128 KB window, L2-resident
            (__float_as_uint(iou) & 0xFFFFFFE0u) | (unsigned)ppt[it];
    }
}

// ---- kB: 8 priors/thread; reads match, applies the per-truth override IN
// REGISTERS from bpk (kOver deleted); per-truth data staged in LDS; lse/losses;
// lcpp/confb; LDS-atomic hist; positive-BCE accumulated here (cnf in registers).
__global__ __launch_bounds__(256) void kB(const float* __restrict__ targets,
                                          const float4* __restrict__ priors,
                                          const float2* __restrict__ loc,
                                          const float4* __restrict__ cnf,
                                          const float* __restrict__ reg,
                                          const unsigned long long* __restrict__ bpk,
                                          const unsigned* __restrict__ match,
                                          float* __restrict__ lcpp,
                                          unsigned char* __restrict__ confb,
                                          unsigned* __restrict__ hist,
                                          double* __restrict__ acc,
                                          int* __restrict__ npos) {
    const int b = blockIdx.y, tid = threadIdx.x;
    const int base = blockIdx.x * 2048;
    __shared__ unsigned lh[1024];
    __shared__ float4 tg[NOBJ];                           // {cx, cy, t5, bitcast(label)}
    lh[tid] = 0; lh[tid + 256] = 0; lh[tid + 512] = 0; lh[tid + 768] = 0;
    if (tid < NOBJ) {
        const float* t = targets + (b * NOBJ + tid) * 6;
        float4 v;
        v.x = (t[0] + t[2]) * 0.5f;                       // same expr/order as reference cx
        v.y = (t[1] + t[3]) * 0.5f;
        v.z = t[5];
        v.w = __int_as_float((int)t[4]);
        tg[tid] = v;
    }

    const size_t bb = (size_t)b * NPRI + base;
    const unsigned* mp = match + bb;
    const float4* cp = cnf + bb;
    float* lp = lcpp + bb;
    unsigned char* cbp = confb + bb;

    unsigned mu[8]; float4 x[8];
    #pragma unroll
    for (int j = 0; j < 8; ++j) mu[j] = mp[j * 256 + tid];
    #pragma unroll
    for (int j = 0; j < 8; ++j) x[j] = cp[j * 256 + tid];

    // per-truth override patch: ascending o == "last o wins" (reference scatter);
    // k==0 -> prior 0 (argmax of an all-zero overlap column is index 0).
    const unsigned long long* bbk = bpk + b * NOBJ;
    #pragma unroll 1
    for (int o = 0; o < NOBJ; ++o) {
        const unsigned long long k = bbk[o];
        const int p = k ? (int)(0xFFFFFFFFu - (unsigned)(k & 0xFFFFFFFFull)) : 0;
        const int q = p - base - tid;
        if (q >= 0 && q < 2048 && (q & 255) == 0) mu[q >> 8] = 0x40000000u | (unsigned)o;
    }

    __syncthreads();                                      // lh zero + tg visible

    const int lane = tid & 63, w = tid >> 6;
    float ll = 0.0f, lr = 0.0f, lbce = 0.0f; int np = 0;
    #pragma unroll
    for (int j = 0; j < 8; ++j) {
        const int ofs = j * 256 + tid;
        const float bto = __uint_as_float(mu[j] & 0xFFFFFFE0u);
        const int bt = (int)(mu[j] & 31u);
        const float4 t4 = tg[bt];                         // LDS broadcast read
        const int c = (bto >= THRSH) ? __float_as_int(t4.w) : 0;
        const float m = fmaxf(fmaxf(x[j].x, x[j].y), fmaxf(x[j].z, x[j].w));
        const float lse = m + logf(expf(x[j].x - m) + expf(x[j].y - m) +
                                   expf(x[j].z - m) + expf(x[j].w - m));
        const float picked = (c == 0) ? x[j].x : (c == 1) ? x[j].y : (c == 2) ? x[j].z : x[j].w;
        const float lval = (c > 0) ? 0.0f : (lse - picked);
        lp[ofs] = lval;
        cbp[ofs] = (unsigned char)c;
        atomicAdd(&lh[__float_as_uint(lval) >> 21], 1u);  // LDS-pipe serialization, VALU-free
        if (c > 0) {                                      // positive: loc/reg losses + BCE here
            const int p = base + ofs;
            const float4 pr = priors[p];
            const float lt0 = (t4.x - pr.x) / (VARNC * pr.z);
            const float lt1 = (t4.y - pr.y) / (VARNC * pr.w);
            const float2 ld = loc[bb + ofs];
            ll += sl1(ld.x - lt0) + sl1(ld.y - lt1);
            lr += sl1(reg[bb + ofs] - t4.z);
            lbce += bce1(x[j].x, false) + bce1(x[j].y, c == 1) +
                    bce1(x[j].z, c == 2) + bce1(x[j].w, c == 3);
            ++np;
        }
    }
    #pragma unroll
    for (int s = 32; s > 0; s >>= 1) {
        ll += __shfl_down(ll, s, 64);
        lr += __shfl_down(lr, s, 64);
        lbce += __shfl_down(lbce, s, 64);
        np += __shfl_down(np, s, 64);
    }
    __shared__ float sred[4][3];
    __shared__ int sredn[4];
    if (lane == 0) { sred[w][0] = ll; sred[w][1] = lr; sred[w][2] = lbce; sredn[w] = np; }
    __syncthreads();                                      // covers lh atomics + sred
    #pragma unroll
    for (int q = 0; q < 4; ++q) {                         // sparse flush
        const unsigned v = lh[tid + q * 256];
        if (v) atomicAdd(&hist[b * 1024 + tid + q * 256], v);
    }
    if (tid == 0) {
        const float tl = sred[0][0] + sred[1][0] + sred[2][0] + sred[3][0];
        const float tr = sred[0][1] + sred[1][1] + sred[2][1] + sred[3][1];
        const float tb2 = sred[0][2] + sred[1][2] + sred[2][2] + sred[3][2];
        const int tn = sredn[0] + sredn[1] + sredn[2] + sredn[3];
        if (tn) {
            atomicAdd(&acc[0], (double)tl);
            atomicAdd(&acc[1], (double)tb2);
            atomicAdd(&acc[2], (double)tr);
            atomicAdd(&npos[b], tn);
        }
    }
}

// ---- kSel: per-batch radix select (T, Istar) by RE-SCANNING the batch's own
// 128 KB lcpp slice (L2-resident after first pass) -- replaces kR2+kR3N, no
// cand list. Then selection-predicate negative-BCE + finalize. ----
__global__ __launch_bounds__(1024) void kSel(const float* __restrict__ lcpp,
                                             const unsigned char* __restrict__ confb,
                                             const float4* __restrict__ cnf,
                                             const unsigned* __restrict__ hist,
                                             const int* __restrict__ npos,
                                             double* __restrict__ acc,
                                             int* __restrict__ done,
                                             float* __restrict__ out) {
    const int b = blockIdx.x, tid = threadIdx.x, lane = tid & 63, w = tid >> 6;
    __shared__ unsigned h[2048];
    __shared__ unsigned wtot[16];
    __shared__ int res[2];
    __shared__ int wsum[16];
    __shared__ int srun, sIstar;
    int k = min(3 * npos[b], NPRI - 1); if (k < 1) k = 1;
    int r = k - 1;

    // level 0: precomputed 1024-bin hist (bins = u>>21)
    {
        const unsigned a = hist[b * 1024 + tid];
        unsigned s = a;
        #pragma unroll
        for (int d = 1; d < 64; d <<= 1) { const unsigned t = __shfl_down(s, d, 64); if (lane + d < 64) s += t; }
        if (lane == 0) wtot[w] = s;
        __syncthreads();
        unsigned add = 0;
        #pragma unroll
        for (int q = 0; q < 16; ++q) if (q > w) add += wtot[q];
        const unsigned Sincl = s + add;
        if (Sincl >= (unsigned)(r + 1) && Sincl - a < (unsigned)(r + 1)) { res[0] = tid; res[1] = r - (int)(Sincl - a); }
        __syncthreads();
    }
    const unsigned B1 = (unsigned)res[0];
    r = res[1];
    const float* lv = lcpp + (size_t)b * NPRI;
    const float4* lv4 = (const float4*)lv;
    __syncthreads();

    // level 1: bits[20:10] among B1 members -- full slice scan (HBM once)
    h[tid] = 0; h[tid + 1024] = 0;
    __syncthreads();
    #pragma unroll 1
    for (int it = 0; it < 8; ++it) {
        const float4 v = lv4[it * 1024 + tid];
        const float vv[4] = {v.x, v.y, v.z, v.w};
        #pragma unroll
        for (int e = 0; e < 4; ++e) {
            const unsigned u = __float_as_uint(vv[e]);
            if ((u >> 21) == B1) atomicAdd(&h[(u >> 10) & 2047u], 1u);
        }
    }
    __syncthreads();
    {
        const unsigned a = h[2 * tid], b2 = h[2 * tid + 1];
        const unsigned sv = a + b2;
        unsigned s = sv;
        #pragma unroll
        for (int d = 1; d < 64; d <<= 1) { const unsigned t = __shfl_down(s, d, 64); if (lane + d < 64) s += t; }
        if (lane == 0) wtot[w] = s;
        __syncthreads();
        unsigned add = 0;
        #pragma unroll
        for (int q = 0; q < 16; ++q) if (q > w) add += wtot[q];
        const unsigned Sincl = s + add;
        const unsigned r1 = (unsigned)(r + 1);
        if (Sincl >= r1 && Sincl - a < r1) { res[0] = 2 * tid; res[1] = r - (int)(Sincl - a); }
        if (Sincl - a >= r1 && Sincl - sv < r1) { res[0] = 2 * tid + 1; res[1] = r - (int)(Sincl - sv); }
        __syncthreads();
    }
    const unsigned P22full = (B1 << 11) | (unsigned)res[0];
    r = res[1];
    __syncthreads();

    // level 2: bits[9:0] among P22 members -- L2-hot re-scan
    h[tid] = 0;
    __syncthreads();
    #pragma unroll 1
    for (int it = 0; it < 8; ++it) {
        const float4 v = lv4[it * 1024 + tid];
        const float vv[4] = {v.x, v.y, v.z, v.w};
        #pragma unroll
        for (int e = 0; e < 4; ++e) {
            const unsigned u = __float_as_uint(vv[e]);
            if ((u >> 10) == P22full) atomicAdd(&h[u & 1023u], 1u);
        }
    }
    __syncthreads();
    {
        const unsigned a = h[tid];
        unsigned s = a;
        #pragma unroll
        for (int d = 1; d < 64; d <<= 1) { const unsigned t = __shfl_down(s, d, 64); if (lane + d < 64) s += t; }
        if (lane == 0) wtot[w] = s;
        __syncthreads();
        unsigned add = 0;
        #pragma unroll
        for (int q = 0; q < 16; ++q) if (q > w) add += wtot[q];
        const unsigned Sincl = s + add;
        if (Sincl >= (unsigned)(r + 1) && Sincl - a < (unsigned)(r + 1)) { res[0] = tid; res[1] = r - (int)(Sincl - a); }
        __syncthreads();
    }
    const unsigned T = (P22full << 10) | (unsigned)res[0];
    const int eq = (int)h[res[0]];
    const int rem = res[1] + 1;

    int Istar = 0x7FFFFFFF;                               // all ties selected (common case)
    if (eq > rem) {                                       // rare: stable cutoff via full scan
        if (tid == 0) { srun = 0; sIstar = 0x7FFFFFFF; }
        __syncthreads();
        for (int chunk = 0; chunk < NPRI / 1024; ++chunk) {
            const int i = chunk * 1024 + tid;
            const bool tie = (__float_as_uint(lv[i]) == T);
            const unsigned long long msk = __ballot(tie);
            if (lane == 0) wsum[w] = __popcll(msk);
            __syncthreads();
            int pre = 0, tot = 0;
            #pragma unroll
            for (int q = 0; q < 16; ++q) { const int c = wsum[q]; if (q < w) pre += c; tot += c; }
            const int myrank = srun + pre + __popcll(msk & ((1ull << lane) - 1ull));
            if (tie && myrank == rem - 1) sIstar = i;
            __syncthreads();
            if (tid == 0) srun += tot;
            __syncthreads();
            if (srun >= rem) break;                       // uniform
        }
        __syncthreads();
        Istar = sIstar;
    }

    // ---- final: predicate scan (L2-hot) + negative-BCE + finalize.
    // bins<B1: u<T auto-excluded; bins>B1: u>T auto-included; B1: tie rule.
    // confb==0 guard excludes positives (counted in kB; lval==0 edge-safe). ----
    const uchar4* cb4 = (const uchar4*)(confb + (size_t)b * NPRI);
    float local = 0.0f;
    #pragma unroll 1
    for (int it = 0; it < 8; ++it) {
        const int i4 = it * 1024 + tid;
        const float4 v = lv4[i4];
        const uchar4 cc = cb4[i4];
        const float vv[4] = {v.x, v.y, v.z, v.w};
        const int cv[4] = {cc.x, cc.y, cc.z, cc.w};
        #pragma unroll
        for (int e = 0; e < 4; ++e) {
            const int i = i4 * 4 + e;
            const unsigned u = __float_as_uint(vv[e]);
            if ((u > T || (u == T && i <= Istar)) && cv[e] == 0) {
                const float4 xx = cnf[(size_t)b * NPRI + i];
                local += bce1(xx.x, true) + bce1(xx.y, false) + bce1(xx.z, false) + bce1(xx.w, false);
            }
        }
    }
    #pragma unroll
    for (int s = 32; s > 0; s >>= 1) local += __shfl_down(local, s, 64);
    if (lane == 0) wtot[w] = __float_as_uint(local);
    __syncthreads();
    __shared__ bool slast;
    if (tid == 0) {
        float t = 0.0f;
        #pragma unroll
        for (int q = 0; q < 16; ++q) t += __uint_as_float(wtot[q]);
        if (t != 0.0f) atomicAdd(&acc[1], (double)t);
        __threadfence();
        const int old = atomicAdd(done, 1);
        slast = (old == BATCH - 1);
    }
    __syncthreads();
    if (slast && tid == 0) {
        __threadfence();
        int nn = 0;
        for (int q = 0; q < BATCH; ++q) nn += npos[q];
        const double a0 = atomicAdd(&acc[0], 0.0);        // atomic-RMW read: cross-XCD safe
        const double a1 = atomicAdd(&acc[1], 0.0);
        const double a2 = atomicAdd(&acc[2], 0.0);
        const double N = (double)nn;
        out[0] = (float)(a0 / N);
        out[1] = (float)(a1 / N);
        out[2] = (float)(a2 / N);
    }
}

extern "C" void kernel_launch(void* const* d_in, const int* in_sizes, int n_in,
                              void* d_out, int out_size, void* d_ws, size_t ws_size,
                              hipStream_t stream) {
    const float* loc = (const float*)d_in[0];
    const float* cnfp = (const float*)d_in[1];
    const float* regp = (const float*)d_in[2];
    const float* tgt = (const float*)d_in[3];
    const float* pri = (const float*)d_in[4];

    char* ws = (char*)d_ws;
    double* acc = (double*)(ws + OFF_ACC);
    int* done = (int*)(ws + OFF_DONE);
    int* npos = (int*)(ws + OFF_NPOS);
    unsigned long long* bpk = (unsigned long long*)(ws + OFF_BPK);
    unsigned* hist = (unsigned*)(ws + OFF_HIST);
    unsigned* match = (unsigned*)(ws + OFF_MATCH);
    float* lcpp = (float*)(ws + OFF_LCPP);
    float4* sp = (float4*)(ws + OFF_SP);
    unsigned* sidx = (unsigned*)(ws + OFF_SIDX);
    unsigned* cello = (unsigned*)(ws + OFF_CELLO);
    unsigned* histS = (unsigned*)(ws + OFF_HISTS);
    unsigned char* confb = (unsigned char*)(ws + OFF_CONF);

    kHist<<<16, 256, 0, stream>>>((const float4*)pri, histS);
    kScan<<<1, 256, 0, stream>>>(histS, cello, (unsigned*)ws);   // also zeroes header
    kScat<<<16, 256, 0, stream>>>((const float4*)pri, cello, sp, sidx);
    kMatch<<<dim3(16, BATCH), 256, 0, stream>>>(tgt, (const float4*)sp, sidx, bpk, match, hist);
    kB<<<dim3(16, BATCH), 256, 0, stream>>>(tgt, (const float4*)pri, (const float2*)loc,
                                            (const float4*)cnfp, regp, bpk, match,
                                            lcpp, confb, hist, acc, npos);
    kSel<<<BATCH, 1024, 0, stream>>>(lcpp, confb, (const float4*)cnfp, hist, npos,
                                     acc, done, (float*)d_out);
}

// Round 10
// 297.605 us; speedup vs baseline: 1.2489x; 1.2489x over previous
//
#include <hip/hip_runtime.h>
#include <math.h>

#define BATCH 128
#define NPRI  32768
#define NOBJ  20
#define THRSH 0.5f
#define VARNC 0.1f

// ---- workspace layout (~37 MB) ----
#define OFF_ACC   0                      // 3 doubles
#define OFF_DONE  48                     // int
#define OFF_NPOS  64                     // 128 ints
#define OFF_CNT   576                    // 128 ints (B1-member counts)
#define OFF_CNTA  1088                   // 128 ints (strictly-above counts)
#define OFF_BPK   2048                   // 2560 ull (zeroed by kScan; filled via atomicMax)
#define OFF_HIST  32768                  // 128*1024 uint = 512 KB (zeroed by kMatch)
#define OFF_MATCH (1 << 20)              // 16 MB u32: (iou_bits & ~31) | best_truth_idx
#define OFF_CAND  (1 << 20)              // u32 INDICES, ALIASES match (dead after kB):
                                         //   front = bin==B1 members, back = bin>B1 members
#define OFF_LCPP  (17 << 20)             // 16 MB float
// sort scratch ALIASES lcpp head (dead before kB writes lcpp):
#define OFF_SP    (17 << 20)             // 512 KB float4 sorted priors
#define OFF_SIDX  ((17 << 20) + (512 << 10))  // 128 KB u32 orig idx
#define OFF_CELLO ((17 << 20) + (640 << 10))  // 1 KB u32 cell offsets
#define OFF_HISTS ((17 << 20) + (644 << 10))  // 16 KB u32: 16 private 256-cell slices
#define OFF_CONF  (33 << 20)             // 4 MB bytes
#define HDR_WORDS 6144                   // 24576 B header zeroed by kScan

__device__ __forceinline__ float sl1(float d) {
    d = fabsf(d);
    return (d < 1.0f) ? 0.5f * d * d : d - 0.5f;
}
__device__ __forceinline__ float bce1(float x, bool hot) {
    float tgt = hot ? 0.925f : 0.025f;
    return fmaxf(x, 0.0f) - x * tgt + log1pf(expf(-fabsf(x)));
}
// 16x16 Morton cell from prior center (spatial locality for consecutive sorted ids)
__device__ __forceinline__ unsigned mortonCell(float cx, float cy) {
    int ix = (int)(cx * 16.0f); ix = min(max(ix, 0), 15);
    int iy = (int)(cy * 16.0f); iy = min(max(iy, 0), 15);
    return (unsigned)((ix & 1) | ((iy & 1) << 1) | ((ix & 2) << 1) | ((iy & 2) << 2)
                    | ((ix & 4) << 2) | ((iy & 4) << 3) | ((ix & 8) << 3) | ((iy & 8) << 4));
}

// ---- kHist: per-block PRIVATE 256-cell slices (no global atomics, no pre-zero) ----
__global__ __launch_bounds__(256) void kHist(const float4* __restrict__ priors,
                                             unsigned* __restrict__ histS) {
    __shared__ unsigned lc[256];
    lc[threadIdx.x] = 0;
    __syncthreads();
    const int i0 = blockIdx.x * 2048 + threadIdx.x;
    for (int j = 0; j < 8; ++j) {
        const float4 p = priors[i0 + j * 256];
        atomicAdd(&lc[mortonCell(p.x, p.y)], 1u);
    }
    __syncthreads();
    histS[blockIdx.x * 256 + threadIdx.x] = lc[threadIdx.x];   // own slice: plain store
}

// ---- kScan: sum 16 slices + exclusive scan of 256 cells; ALSO zeroes the header
// (acc/done/npos/cnt/cntA/bpk) -- replaces the hipMemsetAsync dispatch. ----
__global__ __launch_bounds__(256) void kScan(const unsigned* __restrict__ histS,
                                             unsigned* __restrict__ cellOff,
                                             unsigned* __restrict__ hdr) {
    const int tid = threadIdx.x, lane = tid & 63, w = tid >> 6;
    for (int k = tid; k < HDR_WORDS; k += 256) hdr[k] = 0;
    unsigned s = 0;
    #pragma unroll
    for (int k = 0; k < 16; ++k) s += histS[k * 256 + tid];
    unsigned inc = s;
    #pragma unroll
    for (int d = 1; d < 64; d <<= 1) { const unsigned t = __shfl_up(inc, d, 64); if (lane >= d) inc += t; }
    __shared__ unsigned wt[4];
    if (lane == 63) wt[w] = inc;
    __syncthreads();
    unsigned woff = 0;
    #pragma unroll
    for (int q = 0; q < 4; ++q) if (q < w) woff += wt[q];
    cellOff[tid] = woff + inc - s;                        // exclusive offset
}

// ---- kScat: counting-sort scatter. Order within a cell is nondeterministic but
// results are order-invariant: all argmax keys use ORIGINAL prior indices. ----
__global__ __launch_bounds__(256) void kScat(const float4* __restrict__ priors,
                                             unsigned* __restrict__ cellOff,
                                             float4* __restrict__ sp,
                                             unsigned* __restrict__ sidx) {
    const int i0 = blockIdx.x * 2048 + threadIdx.x;
    for (int j = 0; j < 8; ++j) {
        const int i = i0 + j * 256;
        const float4 p = priors[i];
        const unsigned pos = atomicAdd(&cellOff[mortonCell(p.x, p.y)], 1u);
        sp[pos] = p; sidx[pos] = (unsigned)i;
    }
}

// ---- kMatch (broad-phase): each wave owns 512 spatially-contiguous sorted priors.
// Per truth: wave-bbox reject skips the IoU body (~90% of tests). One IoU pass
// feeds BOTH argmax chains; per-prior results scatter to original indices. ----
__global__ __launch_bounds__(256) void kMatch(const float* __restrict__ targets,
                                              const float4* __restrict__ sp,
                                              const unsigned* __restrict__ sidx,
                                              unsigned long long* __restrict__ bpk,
                                              unsigned* __restrict__ match,
                                              unsigned* __restrict__ hist) {
    const int b = blockIdx.y, tid = threadIdx.x, lane = tid & 63, w = tid >> 6;
    const float* tb = targets + b * NOBJ * 6;            // block-uniform -> s_loads
    const int xb = blockIdx.x;                           // 0..15
    if (tid < 64) hist[b * 1024 + xb * 64 + tid] = 0;    // re-zero hist every launch
    const int wbase = xb * 2048 + w * 512;

    float px0[8], py0[8], px1[8], py1[8], ab[8]; unsigned op[8];
    #pragma unroll
    for (int it = 0; it < 8; ++it) {
        const int si = wbase + it * 64 + lane;           // coalesced within wave
        const float4 pr = sp[si];
        op[it] = sidx[si];
        px0[it] = pr.x - pr.z * 0.5f; py0[it] = pr.y - pr.w * 0.5f;
        px1[it] = pr.x + pr.z * 0.5f; py1[it] = pr.y + pr.w * 0.5f;
        ab[it] = (px1[it] - px0[it]) * (py1[it] - py0[it]);
    }
    // wave bbox (identical in all lanes after butterfly)
    float bx0 = px0[0], by0 = py0[0], bx1 = px1[0], by1 = py1[0];
    #pragma unroll
    for (int it = 1; it < 8; ++it) {
        bx0 = fminf(bx0, px0[it]); by0 = fminf(by0, py0[it]);
        bx1 = fmaxf(bx1, px1[it]); by1 = fmaxf(by1, py1[it]);
    }
    #pragma unroll
    for (int s = 32; s > 0; s >>= 1) {
        bx0 = fminf(bx0, __shfl_xor(bx0, s, 64)); by0 = fminf(by0, __shfl_xor(by0, s, 64));
        bx1 = fmaxf(bx1, __shfl_xor(bx1, s, 64)); by1 = fmaxf(by1, __shfl_xor(by1, s, 64));
    }
    // neutral init == (iou 0, truth 0): exactly reference's all-zero-row argmax
    float ppi[8], ppd[8]; int ppt[8];
    #pragma unroll
    for (int it = 0; it < 8; ++it) { ppi[it] = 0.0f; ppd[it] = 1.0f; ppt[it] = 0; }

    __shared__ unsigned long long red[NOBJ];
    if (tid < NOBJ) red[tid] = 0ull;
    __syncthreads();

    #pragma unroll 1
    for (int o = 0; o < NOBJ; ++o) {
        const float t0 = tb[o * 6], t1 = tb[o * 6 + 1], t2 = tb[o * 6 + 2], t3 = tb[o * 6 + 3];
        // conservative reject: bbox disjoint -> all inter==0 -> no chain update possible
        if (t2 > bx0 && t3 > by0 && t0 < bx1 && t1 < by1) {
            const float aa = (t2 - t0) * (t3 - t1);
            float tbi = -1.0f, tbd = 1.0f; int tbp = 0;
            #pragma unroll
            for (int it = 0; it < 8; ++it) {
                float ix = fminf(t2, px1[it]) - fmaxf(t0, px0[it]); ix = fmaxf(ix, 0.0f);
                float iy = fminf(t3, py1[it]) - fmaxf(t1, py0[it]); iy = fmaxf(iy, 0.0f);
                const float inter = ix * iy;
                const float den = aa + ab[it] - inter;
                // per-prior best (argmax over truths; strict > keeps first o on tie)
                if (inter * ppd[it] > ppi[it] * den) { ppi[it] = inter; ppd[it] = den; ppt[it] = o; }
                // per-truth best (fires at it=0: inter>=0 > -den)
                if (inter * tbd > tbi * den) { tbi = inter; tbd = den; tbp = (int)op[it]; }
            }
            const float iou = tbi / tbd;                 // exact div: same ordering as reference
            unsigned long long key = ((unsigned long long)__float_as_uint(iou) << 32)
                                   | (unsigned long long)(0xFFFFFFFFu - (unsigned)tbp);
            #pragma unroll
            for (int s = 32; s > 0; s >>= 1) {
                unsigned long long k2 = __shfl_xor(key, s, 64);
                if (k2 > key) key = k2;
            }
            if (lane == 0) atomicMax(&red[o], key);
        }
    }
    __syncthreads();
    if (tid < NOBJ && red[tid]) atomicMax(&bpk[b * NOBJ + tid], red[tid]);

    #pragma unroll
    for (int it = 0; it < 8; ++it) {
        const float iou = ppi[it] / ppd[it];             // same div order as reference
        match[(size_t)b * NPRI + op[it]] =               // scatter: 128 KB window, L2-resident
            (__float_as_uint(iou) & 0xFFFFFFE0u) | (unsigned)ppt[it];
    }
}

// ---- kB: 8 priors/thread; reads match; per-truth override positions staged in
// LDS (20 parallel decodes, no per-wave serial scalar loads); per-truth data in
// LDS; lse/losses; lcpp/confb; LDS-atomic hist; positive-BCE accumulated here. ----
__global__ __launch_bounds__(256) void kB(const float* __restrict__ targets,
                                          const float4* __restrict__ priors,
                                          const float2* __restrict__ loc,
                                          const float4* __restrict__ cnf,
                                          const float* __restrict__ reg,
                                          const unsigned long long* __restrict__ bpk,
                                          const unsigned* __restrict__ match,
                                          float* __restrict__ lcpp,
                                          unsigned char* __restrict__ confb,
                                          unsigned* __restrict__ hist,
                                          double* __restrict__ acc,
                                          int* __restrict__ npos) {
    const int b = blockIdx.y, tid = threadIdx.x;
    const int base = blockIdx.x * 2048;
    __shared__ unsigned lh[1024];
    __shared__ float4 tg[NOBJ];                           // {cx, cy, t5, bitcast(label)}
    __shared__ int po[NOBJ];                              // override positions (decoded once)
    lh[tid] = 0; lh[tid + 256] = 0; lh[tid + 512] = 0; lh[tid + 768] = 0;
    if (tid < NOBJ) {
        const float* t = targets + (b * NOBJ + tid) * 6;
        float4 v;
        v.x = (t[0] + t[2]) * 0.5f;                       // same expr/order as reference cx
        v.y = (t[1] + t[3]) * 0.5f;
        v.z = t[5];
        v.w = __int_as_float((int)t[4]);
        tg[tid] = v;
        // k==0 -> prior 0 (argmax of an all-zero overlap column is index 0)
        const unsigned long long k = bpk[b * NOBJ + tid];
        po[tid] = k ? (int)(0xFFFFFFFFu - (unsigned)(k & 0xFFFFFFFFull)) : 0;
    }

    const size_t bb = (size_t)b * NPRI + base;
    const unsigned* mp = match + bb;
    const float4* cp = cnf + bb;
    float* lp = lcpp + bb;
    unsigned char* cbp = confb + bb;

    unsigned mu[8]; float4 x[8];
    #pragma unroll
    for (int j = 0; j < 8; ++j) mu[j] = mp[j * 256 + tid];
    #pragma unroll
    for (int j = 0; j < 8; ++j) x[j] = cp[j * 256 + tid];

    __syncthreads();                                      // lh zero + tg + po visible

    // per-truth override patch: ascending o == "last o wins" (reference scatter)
    #pragma unroll 1
    for (int o = 0; o < NOBJ; ++o) {
        const int q = po[o] - base - tid;                 // LDS broadcast read
        if (q >= 0 && q < 2048 && (q & 255) == 0) mu[q >> 8] = 0x40000000u | (unsigned)o;
    }

    const int lane = tid & 63, w = tid >> 6;
    float ll = 0.0f, lr = 0.0f, lbce = 0.0f; int np = 0;
    #pragma unroll
    for (int j = 0; j < 8; ++j) {
        const int ofs = j * 256 + tid;
        const float bto = __uint_as_float(mu[j] & 0xFFFFFFE0u);
        const int bt = (int)(mu[j] & 31u);
        const float4 t4 = tg[bt];                         // LDS broadcast read
        const int c = (bto >= THRSH) ? __float_as_int(t4.w) : 0;
        const float m = fmaxf(fmaxf(x[j].x, x[j].y), fmaxf(x[j].z, x[j].w));
        const float lse = m + logf(expf(x[j].x - m) + expf(x[j].y - m) +
                                   expf(x[j].z - m) + expf(x[j].w - m));
        const float picked = (c == 0) ? x[j].x : (c == 1) ? x[j].y : (c == 2) ? x[j].z : x[j].w;
        const float lval = (c > 0) ? 0.0f : (lse - picked);
        lp[ofs] = lval;
        cbp[ofs] = (unsigned char)c;
        atomicAdd(&lh[__float_as_uint(lval) >> 21], 1u);  // LDS-pipe serialization, VALU-free
        if (c > 0) {                                      // positive: loc/reg losses + BCE here
            const int p = base + ofs;
            const float4 pr = priors[p];
            const float lt0 = (t4.x - pr.x) / (VARNC * pr.z);
            const float lt1 = (t4.y - pr.y) / (VARNC * pr.w);
            const float2 ld = loc[bb + ofs];
            ll += sl1(ld.x - lt0) + sl1(ld.y - lt1);
            lr += sl1(reg[bb + ofs] - t4.z);
            lbce += bce1(x[j].x, false) + bce1(x[j].y, c == 1) +
                    bce1(x[j].z, c == 2) + bce1(x[j].w, c == 3);
            ++np;
        }
    }
    #pragma unroll
    for (int s = 32; s > 0; s >>= 1) {
        ll += __shfl_down(ll, s, 64);
        lr += __shfl_down(lr, s, 64);
        lbce += __shfl_down(lbce, s, 64);
        np += __shfl_down(np, s, 64);
    }
    __shared__ float sred[4][3];
    __shared__ int sredn[4];
    if (lane == 0) { sred[w][0] = ll; sred[w][1] = lr; sred[w][2] = lbce; sredn[w] = np; }
    __syncthreads();                                      // covers lh atomics + sred
    #pragma unroll
    for (int q = 0; q < 4; ++q) {                         // sparse flush
        const unsigned v = lh[tid + q * 256];
        if (v) atomicAdd(&hist[b * 1024 + tid + q * 256], v);
    }
    if (tid == 0) {
        const float tl = sred[0][0] + sred[1][0] + sred[2][0] + sred[3][0];
        const float tr = sred[0][1] + sred[1][1] + sred[2][1] + sred[3][1];
        const float tb2 = sred[0][2] + sred[1][2] + sred[2][2] + sred[3][2];
        const int tn = sredn[0] + sredn[1] + sredn[2] + sredn[3];
        if (tn) {
            atomicAdd(&acc[0], (double)tl);
            atomicAdd(&acc[1], (double)tb2);
            atomicAdd(&acc[2], (double)tr);
            atomicAdd(&npos[b], tn);
        }
    }
}

// ---- kR2: derive B1; compact INDICES of bin==B1 (front) and bin>B1 (back).
// 16 blocks/batch (8 elements/thread) for occupancy. ----
__global__ __launch_bounds__(256) void kR2(const float* __restrict__ lcpp,
                                           const unsigned* __restrict__ hist,
                                           const int* __restrict__ npos,
                                           unsigned* __restrict__ cand,
                                           int* __restrict__ cnt,
                                           int* __restrict__ cntA) {
    const int b = blockIdx.y, tid = threadIdx.x, lane = tid & 63, w = tid >> 6;
    __shared__ unsigned wtot[4];
    __shared__ int resB;
    int k = min(3 * npos[b], NPRI - 1); if (k < 1) k = 1;
    const unsigned r1 = (unsigned)k;
    const unsigned h0 = hist[b * 1024 + 4 * tid],     h1 = hist[b * 1024 + 4 * tid + 1],
                   h2 = hist[b * 1024 + 4 * tid + 2], h3 = hist[b * 1024 + 4 * tid + 3];
    const unsigned sv = h0 + h1 + h2 + h3;
    unsigned s = sv;
    #pragma unroll
    for (int d = 1; d < 64; d <<= 1) { const unsigned t = __shfl_down(s, d, 64); if (lane + d < 64) s += t; }
    if (lane == 0) wtot[w] = s;
    __syncthreads();
    unsigned add = 0;
    #pragma unroll
    for (int q = 0; q < 4; ++q) if (q > w) add += wtot[q];
    const unsigned suf = s + add;
    if (suf >= r1 && suf - h0 < r1) resB = 4 * tid;
    if (suf - h0 >= r1 && suf - h0 - h1 < r1) resB = 4 * tid + 1;
    if (suf - h0 - h1 >= r1 && suf - h0 - h1 - h2 < r1) resB = 4 * tid + 2;
    if (suf - h0 - h1 - h2 >= r1 && suf - sv < r1) resB = 4 * tid + 3;
    __syncthreads();
    const unsigned B1 = (unsigned)resB;

    const float4* v4 = (const float4*)(lcpp + (size_t)b * NPRI);
    const int base4 = blockIdx.x * 512;
    float4 xx[2];
    #pragma unroll
    for (int it = 0; it < 2; ++it) xx[it] = v4[base4 + it * 256 + tid];
    const float* xe = (const float*)xx;
    int myc = 0, mya = 0;
    #pragma unroll
    for (int e = 0; e < 8; ++e) {
        const unsigned bin = __float_as_uint(xe[e]) >> 21;
        myc += (bin == B1);
        mya += (bin > B1);
    }
    // packed dual block-exclusive scan (each field <= 8, block sums < 65536)
    const int pk = myc | (mya << 16);
    int inc = pk;
    #pragma unroll
    for (int d = 1; d < 64; d <<= 1) { const int t = __shfl_up(inc, d, 64); if (lane >= d) inc += t; }
    __shared__ int wt[4];
    __shared__ int sbase, sbaseA;
    if (lane == 63) wt[w] = inc;
    __syncthreads();
    int woff = 0;
    #pragma unroll
    for (int q = 0; q < 4; ++q) if (q < w) woff += wt[q];
    if (tid == 0) {
        const int tot = wt[0] + wt[1] + wt[2] + wt[3];
        sbase = atomicAdd(&cnt[b], tot & 0xFFFF);
        sbaseA = atomicAdd(&cntA[b], tot >> 16);
    }
    __syncthreads();
    const int ex = inc - pk;                              // packed exclusive within-thread base
    int pc = sbase + (woff & 0xFFFF) + (ex & 0xFFFF);
    int pa = sbaseA + (woff >> 16) + (ex >> 16);
    unsigned* cb = cand + (size_t)b * NPRI;
    #pragma unroll
    for (int e = 0; e < 8; ++e) {
        const unsigned bin = __float_as_uint(xe[e]) >> 21;
        const unsigned idx = (unsigned)(((base4 + (e >> 2) * 256 + tid) << 2) | (e & 3));
        if (bin == B1) cb[pc++] = idx;
        else if (bin > B1) cb[NPRI - 1 - pa++] = idx;
    }
}

// ---- kR3N: exact T + tie cutoff among B1-member INDICES, then (same block)
// the compacted negative-BCE + finalize. ----
__global__ __launch_bounds__(1024) void kR3N(const float* __restrict__ lcpp,
                                             const unsigned char* __restrict__ confb,
                                             const float4* __restrict__ cnf,
                                             const unsigned* __restrict__ hist,
                                             const int* __restrict__ npos,
                                             const unsigned* __restrict__ cand,
                                             const int* __restrict__ cnt,
                                             const int* __restrict__ cntA,
                                             double* __restrict__ acc,
                                             int* __restrict__ done,
                                             float* __restrict__ out) {
    const int b = blockIdx.x, tid = threadIdx.x, lane = tid & 63, w = tid >> 6;
    __shared__ unsigned h[2048];
    __shared__ unsigned wtot[16];
    __shared__ int res[2];
    __shared__ int wsum[16];
    __shared__ int srun, sIstar;
    int k = min(3 * npos[b], NPRI - 1); if (k < 1) k = 1;
    int r = k - 1;

    // level 0: precomputed 1024-bin hist
    {
        const unsigned a = hist[b * 1024 + tid];
        unsigned s = a;
        #pragma unroll
        for (int d = 1; d < 64; d <<= 1) { const unsigned t = __shfl_down(s, d, 64); if (lane + d < 64) s += t; }
        if (lane == 0) wtot[w] = s;
        __syncthreads();
        unsigned add = 0;
        #pragma unroll
        for (int q = 0; q < 16; ++q) if (q > w) add += wtot[q];
        const unsigned Sincl = s + add;
        if (Sincl >= (unsigned)(r + 1) && Sincl - a < (unsigned)(r + 1)) { res[0] = tid; res[1] = r - (int)(Sincl - a); }
        __syncthreads();
    }
    r = res[1];
    const int n = cnt[b];
    const unsigned* cd = cand + (size_t)b * NPRI;
    const float* lv = lcpp + (size_t)b * NPRI;
    __syncthreads();

    // level 1: bits[20:10] among B1 members (values gathered via indices)
    h[tid] = 0; h[tid + 1024] = 0;
    __syncthreads();
    for (int i = tid; i < n; i += 1024)
        atomicAdd(&h[(__float_as_uint(lv[cd[i]]) >> 10) & 2047u], 1u);
    __syncthreads();
    {
        const unsigned a = h[2 * tid], b2 = h[2 * tid + 1];
        const unsigned sv = a + b2;
        unsigned s = sv;
        #pragma unroll
        for (int d = 1; d < 64; d <<= 1) { const unsigned t = __shfl_down(s, d, 64); if (lane + d < 64) s += t; }
        if (lane == 0) wtot[w] = s;
        __syncthreads();
        unsigned add = 0;
        #pragma unroll
        for (int q = 0; q < 16; ++q) if (q > w) add += wtot[q];
        const unsigned Sincl = s + add;
        const unsigned r1 = (unsigned)(r + 1);
        if (Sincl >= r1 && Sincl - a < r1) { res[0] = 2 * tid; res[1] = r - (int)(Sincl - a); }
        if (Sincl - a >= r1 && Sincl - sv < r1) { res[0] = 2 * tid + 1; res[1] = r - (int)(Sincl - sv); }
        __syncthreads();
    }
    const unsigned B1 = n > 0 ? (__float_as_uint(lv[cd[0]]) >> 21) : 0u;
    const unsigned P22full = (B1 << 11) | (unsigned)res[0];
    r = res[1];
    __syncthreads();

    // level 2: bits[9:0] among P22 candidates
    h[tid] = 0;
    __syncthreads();
    for (int i = tid; i < n; i += 1024) {
        const unsigned u = __float_as_uint(lv[cd[i]]);
        if ((u >> 10) == P22full) atomicAdd(&h[u & 1023u], 1u);
    }
    __syncthreads();
    {
        const unsigned a = h[tid];
        unsigned s = a;
        #pragma unroll
        for (int d = 1; d < 64; d <<= 1) { const unsigned t = __shfl_down(s, d, 64); if (lane + d < 64) s += t; }
        if (lane == 0) wtot[w] = s;
        __syncthreads();
        unsigned add = 0;
        #pragma unroll
        for (int q = 0; q < 16; ++q) if (q > w) add += wtot[q];
        const unsigned Sincl = s + add;
        if (Sincl >= (unsigned)(r + 1) && Sincl - a < (unsigned)(r + 1)) { res[0] = tid; res[1] = r - (int)(Sincl - a); }
        __syncthreads();
    }
    const unsigned T = (P22full << 10) | (unsigned)res[0];
    const int eq = (int)h[res[0]];
    const int rem = res[1] + 1;

    int Istar = 0x7FFFFFFF;                               // all ties selected (common case)
    if (eq > rem) {                                       // rare: stable cutoff via full scan
        if (tid == 0) { srun = 0; sIstar = 0x7FFFFFFF; }
        __syncthreads();
        for (int chunk = 0; chunk < NPRI / 1024; ++chunk) {
            const int i = chunk * 1024 + tid;
            const bool tie = (__float_as_uint(lv[i]) == T);
            const unsigned long long msk = __ballot(tie);
            if (lane == 0) wsum[w] = __popcll(msk);
            __syncthreads();
            int pre = 0, tot = 0;
            #pragma unroll
            for (int q = 0; q < 16; ++q) { const int c = wsum[q]; if (q < w) pre += c; tot += c; }
            const int myrank = srun + pre + __popcll(msk & ((1ull << lane) - 1ull));
            if (tie && myrank == rem - 1) sIstar = i;
            __syncthreads();
            if (tid == 0) srun += tot;
            __syncthreads();
            if (srun >= rem) break;                       // uniform
        }
        __syncthreads();
        Istar = sIstar;
    }

    // ---- negative-BCE over compacted lists + finalize ----
    const int nA = cntA[b];
    float local = 0.0f;
    for (int i = tid; i < nA; i += 1024) {                // strictly-above: all selected
        const unsigned idx = cd[NPRI - 1 - i];
        const float4 xx = cnf[(size_t)b * NPRI + idx];
        local += bce1(xx.x, true) + bce1(xx.y, false) + bce1(xx.z, false) + bce1(xx.w, false);
    }
    for (int i = tid; i < n; i += 1024) {                 // B1 bin: tie rule
        const unsigned idx = cd[i];
        const unsigned u = __float_as_uint(lv[idx]);
        if ((u > T || (u == T && (int)idx <= Istar)) && confb[(size_t)b * NPRI + idx] == 0) {
            const float4 xx = cnf[(size_t)b * NPRI + idx];
            local += bce1(xx.x, true) + bce1(xx.y, false) + bce1(xx.z, false) + bce1(xx.w, false);
        }
    }
    #pragma unroll
    for (int s = 32; s > 0; s >>= 1) local += __shfl_down(local, s, 64);
    if (lane == 0) wtot[w] = __float_as_uint(local);
    __syncthreads();
    __shared__ bool slast;
    if (tid == 0) {
        float t = 0.0f;
        #pragma unroll
        for (int q = 0; q < 16; ++q) t += __uint_as_float(wtot[q]);
        if (t != 0.0f) atomicAdd(&acc[1], (double)t);
        __threadfence();
        const int old = atomicAdd(done, 1);
        slast = (old == BATCH - 1);
    }
    __syncthreads();
    if (slast && tid == 0) {
        __threadfence();
        int nn = 0;
        for (int q = 0; q < BATCH; ++q) nn += npos[q];
        const double a0 = atomicAdd(&acc[0], 0.0);        // atomic-RMW read: cross-XCD safe
        const double a1 = atomicAdd(&acc[1], 0.0);
        const double a2 = atomicAdd(&acc[2], 0.0);
        const double N = (double)nn;
        out[0] = (float)(a0 / N);
        out[1] = (float)(a1 / N);
        out[2] = (float)(a2 / N);
    }
}

extern "C" void kernel_launch(void* const* d_in, const int* in_sizes, int n_in,
                              void* d_out, int out_size, void* d_ws, size_t ws_size,
                              hipStream_t stream) {
    const float* loc = (const float*)d_in[0];
    const float* cnfp = (const float*)d_in[1];
    const float* regp = (const float*)d_in[2];
    const float* tgt = (const float*)d_in[3];
    const float* pri = (const float*)d_in[4];

    char* ws = (char*)d_ws;
    double* acc = (double*)(ws + OFF_ACC);
    int* done = (int*)(ws + OFF_DONE);
    int* npos = (int*)(ws + OFF_NPOS);
    int* cnt = (int*)(ws + OFF_CNT);
    int* cntA = (int*)(ws + OFF_CNTA);
    unsigned long long* bpk = (unsigned long long*)(ws + OFF_BPK);
    unsigned* hist = (unsigned*)(ws + OFF_HIST);
    unsigned* match = (unsigned*)(ws + OFF_MATCH);
    unsigned* cand = (unsigned*)(ws + OFF_CAND);
    float* lcpp = (float*)(ws + OFF_LCPP);
    float4* sp = (float4*)(ws + OFF_SP);
    unsigned* sidx = (unsigned*)(ws + OFF_SIDX);
    unsigned* cello = (unsigned*)(ws + OFF_CELLO);
    unsigned* histS = (unsigned*)(ws + OFF_HISTS);
    unsigned char* confb = (unsigned char*)(ws + OFF_CONF);

    kHist<<<16, 256, 0, stream>>>((const float4*)pri, histS);
    kScan<<<1, 256, 0, stream>>>(histS, cello, (unsigned*)ws);   // also zeroes header
    kScat<<<16, 256, 0, stream>>>((const float4*)pri, cello, sp, sidx);
    kMatch<<<dim3(16, BATCH), 256, 0, stream>>>(tgt, (const float4*)sp, sidx, bpk, match, hist);
    kB<<<dim3(16, BATCH), 256, 0, stream>>>(tgt, (const float4*)pri, (const float2*)loc,
                                            (const float4*)cnfp, regp, bpk, match,
                                            lcpp, confb, hist, acc, npos);
    kR2<<<dim3(16, BATCH), 256, 0, stream>>>(lcpp, hist, npos, cand, cnt, cntA);
    kR3N<<<BATCH, 1024, 0, stream>>>(lcpp, confb, (const float4*)cnfp, hist, npos,
                                     cand, cnt, cntA, acc, done, (float*)d_out);
}

// Round 11
// 290.065 us; speedup vs baseline: 1.2814x; 1.0260x over previous
//
#include <hip/hip_runtime.h>
#include <math.h>

#define BATCH 128
#define NPRI  32768
#define NOBJ  20
#define THRSH 0.5f
#define VARNC 0.1f

// ---- workspace layout (~37 MB) ----
#define OFF_ACC   0                      // 3 doubles
#define OFF_DONE  48                     // int
#define OFF_NPOS  64                     // 128 ints
#define OFF_CNT   576                    // 128 ints (B1-member counts)
#define OFF_CNTA  1088                   // 128 ints (strictly-above counts)
#define OFF_BPK   2048                   // 2560 ull (zeroed by kScan; filled via atomicMax)
#define OFF_HIST  32768                  // 128*1024 uint = 512 KB (zeroed by kMatch)
#define OFF_MATCH (1 << 20)              // 4 MB uchar: (sel<<5) | best_truth_idx
#define OFF_CAND  (1 << 20)              // u32 INDICES, ALIASES matchb (dead after kB):
                                         //   front = bin==B1 members, back = bin>B1 members
#define OFF_LCPP  (17 << 20)             // 16 MB float
// sort scratch ALIASES lcpp head (dead before kB writes lcpp):
#define OFF_SP    (17 << 20)             // 512 KB float4 sorted priors
#define OFF_SIDX  ((17 << 20) + (512 << 10))  // 128 KB u32 orig idx
#define OFF_CELLO ((17 << 20) + (640 << 10))  // 1 KB u32 cell offsets
#define OFF_HISTS ((17 << 20) + (644 << 10))  // 16 KB u32: 16 private 256-cell slices
#define OFF_CONF  (33 << 20)             // 4 MB bytes
#define HDR_WORDS 6144                   // 24576 B header zeroed by kScan

__device__ __forceinline__ float sl1(float d) {
    d = fabsf(d);
    return (d < 1.0f) ? 0.5f * d * d : d - 0.5f;
}
__device__ __forceinline__ float bce1(float x, bool hot) {
    float tgt = hot ? 0.925f : 0.025f;
    return fmaxf(x, 0.0f) - x * tgt + log1pf(expf(-fabsf(x)));
}
// 16x16 Morton cell from prior center (spatial locality for consecutive sorted ids)
__device__ __forceinline__ unsigned mortonCell(float cx, float cy) {
    int ix = (int)(cx * 16.0f); ix = min(max(ix, 0), 15);
    int iy = (int)(cy * 16.0f); iy = min(max(iy, 0), 15);
    return (unsigned)((ix & 1) | ((iy & 1) << 1) | ((ix & 2) << 1) | ((iy & 2) << 2)
                    | ((ix & 4) << 2) | ((iy & 4) << 3) | ((ix & 8) << 3) | ((iy & 8) << 4));
}

// ---- kHist: per-block PRIVATE 256-cell slices (no global atomics, no pre-zero) ----
__global__ __launch_bounds__(256) void kHist(const float4* __restrict__ priors,
                                             unsigned* __restrict__ histS) {
    __shared__ unsigned lc[256];
    lc[threadIdx.x] = 0;
    __syncthreads();
    const int i0 = blockIdx.x * 2048 + threadIdx.x;
    for (int j = 0; j < 8; ++j) {
        const float4 p = priors[i0 + j * 256];
        atomicAdd(&lc[mortonCell(p.x, p.y)], 1u);
    }
    __syncthreads();
    histS[blockIdx.x * 256 + threadIdx.x] = lc[threadIdx.x];   // own slice: plain store
}

// ---- kScan: sum 16 slices + exclusive scan of 256 cells; ALSO zeroes the header
// (acc/done/npos/cnt/cntA/bpk) -- replaces the hipMemsetAsync dispatch. ----
__global__ __launch_bounds__(256) void kScan(const unsigned* __restrict__ histS,
                                             unsigned* __restrict__ cellOff,
                                             unsigned* __restrict__ hdr) {
    const int tid = threadIdx.x, lane = tid & 63, w = tid >> 6;
    for (int k = tid; k < HDR_WORDS; k += 256) hdr[k] = 0;
    unsigned s = 0;
    #pragma unroll
    for (int k = 0; k < 16; ++k) s += histS[k * 256 + tid];
    unsigned inc = s;
    #pragma unroll
    for (int d = 1; d < 64; d <<= 1) { const unsigned t = __shfl_up(inc, d, 64); if (lane >= d) inc += t; }
    __shared__ unsigned wt[4];
    if (lane == 63) wt[w] = inc;
    __syncthreads();
    unsigned woff = 0;
    #pragma unroll
    for (int q = 0; q < 4; ++q) if (q < w) woff += wt[q];
    cellOff[tid] = woff + inc - s;                        // exclusive offset
}

// ---- kScat: counting-sort scatter. Order within a cell is nondeterministic but
// results are order-invariant: all argmax keys use ORIGINAL prior indices. ----
__global__ __launch_bounds__(256) void kScat(const float4* __restrict__ priors,
                                             unsigned* __restrict__ cellOff,
                                             float4* __restrict__ sp,
                                             unsigned* __restrict__ sidx) {
    const int i0 = blockIdx.x * 2048 + threadIdx.x;
    for (int j = 0; j < 8; ++j) {
        const int i = i0 + j * 256;
        const float4 p = priors[i];
        const unsigned pos = atomicAdd(&cellOff[mortonCell(p.x, p.y)], 1u);
        sp[pos] = p; sidx[pos] = (unsigned)i;
    }
}

// ---- kMatch (broad-phase): each wave owns 512 spatially-contiguous sorted priors.
// Per truth: wave-bbox reject skips the IoU body (~90% of tests). One IoU pass
// feeds BOTH argmax chains. Per-prior result is ONE BYTE: (iou>=0.5)<<5 | truth
// (kB only needs the threshold bit, not the iou magnitude) -> 4x less traffic. ----
__global__ __launch_bounds__(256) void kMatch(const float* __restrict__ targets,
                                              const float4* __restrict__ sp,
                                              const unsigned* __restrict__ sidx,
                                              unsigned long long* __restrict__ bpk,
                                              unsigned char* __restrict__ matchb,
                                              unsigned* __restrict__ hist) {
    const int b = blockIdx.y, tid = threadIdx.x, lane = tid & 63, w = tid >> 6;
    const float* tb = targets + b * NOBJ * 6;            // block-uniform -> s_loads
    const int xb = blockIdx.x;                           // 0..15
    if (tid < 64) hist[b * 1024 + xb * 64 + tid] = 0;    // re-zero hist every launch
    const int wbase = xb * 2048 + w * 512;

    float px0[8], py0[8], px1[8], py1[8], ab[8]; unsigned op[8];
    #pragma unroll
    for (int it = 0; it < 8; ++it) {
        const int si = wbase + it * 64 + lane;           // coalesced within wave
        const float4 pr = sp[si];
        op[it] = sidx[si];
        px0[it] = pr.x - pr.z * 0.5f; py0[it] = pr.y - pr.w * 0.5f;
        px1[it] = pr.x + pr.z * 0.5f; py1[it] = pr.y + pr.w * 0.5f;
        ab[it] = (px1[it] - px0[it]) * (py1[it] - py0[it]);
    }
    // wave bbox (identical in all lanes after butterfly)
    float bx0 = px0[0], by0 = py0[0], bx1 = px1[0], by1 = py1[0];
    #pragma unroll
    for (int it = 1; it < 8; ++it) {
        bx0 = fminf(bx0, px0[it]); by0 = fminf(by0, py0[it]);
        bx1 = fmaxf(bx1, px1[it]); by1 = fmaxf(by1, py1[it]);
    }
    #pragma unroll
    for (int s = 32; s > 0; s >>= 1) {
        bx0 = fminf(bx0, __shfl_xor(bx0, s, 64)); by0 = fminf(by0, __shfl_xor(by0, s, 64));
        bx1 = fmaxf(bx1, __shfl_xor(bx1, s, 64)); by1 = fmaxf(by1, __shfl_xor(by1, s, 64));
    }
    // neutral init == (iou 0, truth 0): exactly reference's all-zero-row argmax
    float ppi[8], ppd[8]; int ppt[8];
    #pragma unroll
    for (int it = 0; it < 8; ++it) { ppi[it] = 0.0f; ppd[it] = 1.0f; ppt[it] = 0; }

    __shared__ unsigned long long red[NOBJ];
    if (tid < NOBJ) red[tid] = 0ull;
    __syncthreads();

    #pragma unroll 1
    for (int o = 0; o < NOBJ; ++o) {
        const float t0 = tb[o * 6], t1 = tb[o * 6 + 1], t2 = tb[o * 6 + 2], t3 = tb[o * 6 + 3];
        // conservative reject: bbox disjoint -> all inter==0 -> no chain update possible
        if (t2 > bx0 && t3 > by0 && t0 < bx1 && t1 < by1) {
            const float aa = (t2 - t0) * (t3 - t1);
            float tbi = -1.0f, tbd = 1.0f; int tbp = 0;
            #pragma unroll
            for (int it = 0; it < 8; ++it) {
                float ix = fminf(t2, px1[it]) - fmaxf(t0, px0[it]); ix = fmaxf(ix, 0.0f);
                float iy = fminf(t3, py1[it]) - fmaxf(t1, py0[it]); iy = fmaxf(iy, 0.0f);
                const float inter = ix * iy;
                const float den = aa + ab[it] - inter;
                // per-prior best (argmax over truths; strict > keeps first o on tie)
                if (inter * ppd[it] > ppi[it] * den) { ppi[it] = inter; ppd[it] = den; ppt[it] = o; }
                // per-truth best (fires at it=0: inter>=0 > -den)
                if (inter * tbd > tbi * den) { tbi = inter; tbd = den; tbp = (int)op[it]; }
            }
            const float iou = tbi / tbd;                 // exact div: same ordering as reference
            unsigned long long key = ((unsigned long long)__float_as_uint(iou) << 32)
                                   | (unsigned long long)(0xFFFFFFFFu - (unsigned)tbp);
            #pragma unroll
            for (int s = 32; s > 0; s >>= 1) {
                unsigned long long k2 = __shfl_xor(key, s, 64);
                if (k2 > key) key = k2;
            }
            if (lane == 0) atomicMax(&red[o], key);
        }
    }
    __syncthreads();
    if (tid < NOBJ && red[tid]) atomicMax(&bpk[b * NOBJ + tid], red[tid]);

    #pragma unroll
    for (int it = 0; it < 8; ++it) {
        const float iou = ppi[it] / ppd[it];             // same div order as reference
        const unsigned sel = (iou >= THRSH) ? 32u : 0u;  // same compare kB used on bto
        matchb[(size_t)b * NPRI + op[it]] =              // scatter: 32 KB window, L2-resident
            (unsigned char)(sel | (unsigned)ppt[it]);
    }
}

// ---- kB: 8 priors/thread; reads 1-byte matchb; per-truth override positions
// staged in LDS (20 parallel decodes); per-truth data in LDS; lse/losses;
// lcpp/confb; LDS-atomic hist; positive-BCE accumulated here. ----
__global__ __launch_bounds__(256) void kB(const float* __restrict__ targets,
                                          const float4* __restrict__ priors,
                                          const float2* __restrict__ loc,
                                          const float4* __restrict__ cnf,
                                          const float* __restrict__ reg,
                                          const unsigned long long* __restrict__ bpk,
                                          const unsigned char* __restrict__ matchb,
                                          float* __restrict__ lcpp,
                                          unsigned char* __restrict__ confb,
                                          unsigned* __restrict__ hist,
                                          double* __restrict__ acc,
                                          int* __restrict__ npos) {
    const int b = blockIdx.y, tid = threadIdx.x;
    const int base = blockIdx.x * 2048;
    __shared__ unsigned lh[1024];
    __shared__ float4 tg[NOBJ];                           // {cx, cy, t5, bitcast(label)}
    __shared__ int po[NOBJ];                              // override positions (decoded once)
    lh[tid] = 0; lh[tid + 256] = 0; lh[tid + 512] = 0; lh[tid + 768] = 0;
    if (tid < NOBJ) {
        const float* t = targets + (b * NOBJ + tid) * 6;
        float4 v;
        v.x = (t[0] + t[2]) * 0.5f;                       // same expr/order as reference cx
        v.y = (t[1] + t[3]) * 0.5f;
        v.z = t[5];
        v.w = __int_as_float((int)t[4]);
        tg[tid] = v;
        // k==0 -> prior 0 (argmax of an all-zero overlap column is index 0)
        const unsigned long long k = bpk[b * NOBJ + tid];
        po[tid] = k ? (int)(0xFFFFFFFFu - (unsigned)(k & 0xFFFFFFFFull)) : 0;
    }

    const size_t bb = (size_t)b * NPRI + base;
    const unsigned char* mp = matchb + bb;
    const float4* cp = cnf + bb;
    float* lp = lcpp + bb;
    unsigned char* cbp = confb + bb;

    int mu[8]; float4 x[8];
    #pragma unroll
    for (int j = 0; j < 8; ++j) mu[j] = (int)mp[j * 256 + tid];
    #pragma unroll
    for (int j = 0; j < 8; ++j) x[j] = cp[j * 256 + tid];

    __syncthreads();                                      // lh zero + tg + po visible

    // per-truth override patch: ascending o == "last o wins" (reference scatter);
    // 64|o > any unpatched value (<=63) in selection priority: c=label(o) forced.
    #pragma unroll 1
    for (int o = 0; o < NOBJ; ++o) {
        const int q = po[o] - base - tid;                 // LDS broadcast read
        if (q >= 0 && q < 2048 && (q & 255) == 0) mu[q >> 8] = 64 | o;
    }

    const int lane = tid & 63, w = tid >> 6;
    float ll = 0.0f, lr = 0.0f, lbce = 0.0f; int np = 0;
    #pragma unroll
    for (int j = 0; j < 8; ++j) {
        const int ofs = j * 256 + tid;
        const int bt = mu[j] & 31;                        // truth idx (override: o)
        const float4 t4 = tg[bt];                         // LDS broadcast read
        const int c = (mu[j] >= 32) ? __float_as_int(t4.w) : 0;   // sel-bit or override-bit
        const float m = fmaxf(fmaxf(x[j].x, x[j].y), fmaxf(x[j].z, x[j].w));
        const float lse = m + logf(expf(x[j].x - m) + expf(x[j].y - m) +
                                   expf(x[j].z - m) + expf(x[j].w - m));
        const float picked = (c == 0) ? x[j].x : (c == 1) ? x[j].y : (c == 2) ? x[j].z : x[j].w;
        const float lval = (c > 0) ? 0.0f : (lse - picked);
        lp[ofs] = lval;
        cbp[ofs] = (unsigned char)c;
        atomicAdd(&lh[__float_as_uint(lval) >> 21], 1u);  // LDS-pipe serialization, VALU-free
        if (c > 0) {                                      // positive: loc/reg losses + BCE here
            const int p = base + ofs;
            const float4 pr = priors[p];
            const float lt0 = (t4.x - pr.x) / (VARNC * pr.z);
            const float lt1 = (t4.y - pr.y) / (VARNC * pr.w);
            const float2 ld = loc[bb + ofs];
            ll += sl1(ld.x - lt0) + sl1(ld.y - lt1);
            lr += sl1(reg[bb + ofs] - t4.z);
            lbce += bce1(x[j].x, false) + bce1(x[j].y, c == 1) +
                    bce1(x[j].z, c == 2) + bce1(x[j].w, c == 3);
            ++np;
        }
    }
    #pragma unroll
    for (int s = 32; s > 0; s >>= 1) {
        ll += __shfl_down(ll, s, 64);
        lr += __shfl_down(lr, s, 64);
        lbce += __shfl_down(lbce, s, 64);
        np += __shfl_down(np, s, 64);
    }
    __shared__ float sred[4][3];
    __shared__ int sredn[4];
    if (lane == 0) { sred[w][0] = ll; sred[w][1] = lr; sred[w][2] = lbce; sredn[w] = np; }
    __syncthreads();                                      // covers lh atomics + sred
    #pragma unroll
    for (int q = 0; q < 4; ++q) {                         // sparse flush
        const unsigned v = lh[tid + q * 256];
        if (v) atomicAdd(&hist[b * 1024 + tid + q * 256], v);
    }
    if (tid == 0) {
        const float tl = sred[0][0] + sred[1][0] + sred[2][0] + sred[3][0];
        const float tr = sred[0][1] + sred[1][1] + sred[2][1] + sred[3][1];
        const float tb2 = sred[0][2] + sred[1][2] + sred[2][2] + sred[3][2];
        const int tn = sredn[0] + sredn[1] + sredn[2] + sredn[3];
        if (tn) {
            atomicAdd(&acc[0], (double)tl);
            atomicAdd(&acc[1], (double)tb2);
            atomicAdd(&acc[2], (double)tr);
            atomicAdd(&npos[b], tn);
        }
    }
}

// ---- kR2: derive B1; compact INDICES of bin==B1 (front) and bin>B1 (back). ----
__global__ __launch_bounds__(256) void kR2(const float* __restrict__ lcpp,
                                           const unsigned* __restrict__ hist,
                                           const int* __restrict__ npos,
                                           unsigned* __restrict__ cand,
                                           int* __restrict__ cnt,
                                           int* __restrict__ cntA) {
    const int b = blockIdx.y, tid = threadIdx.x, lane = tid & 63, w = tid >> 6;
    __shared__ unsigned wtot[4];
    __shared__ int resB;
    int k = min(3 * npos[b], NPRI - 1); if (k < 1) k = 1;
    const unsigned r1 = (unsigned)k;
    const unsigned h0 = hist[b * 1024 + 4 * tid],     h1 = hist[b * 1024 + 4 * tid + 1],
                   h2 = hist[b * 1024 + 4 * tid + 2], h3 = hist[b * 1024 + 4 * tid + 3];
    const unsigned sv = h0 + h1 + h2 + h3;
    unsigned s = sv;
    #pragma unroll
    for (int d = 1; d < 64; d <<= 1) { const unsigned t = __shfl_down(s, d, 64); if (lane + d < 64) s += t; }
    if (lane == 0) wtot[w] = s;
    __syncthreads();
    unsigned add = 0;
    #pragma unroll
    for (int q = 0; q < 4; ++q) if (q > w) add += wtot[q];
    const unsigned suf = s + add;
    if (suf >= r1 && suf - h0 < r1) resB = 4 * tid;
    if (suf - h0 >= r1 && suf - h0 - h1 < r1) resB = 4 * tid + 1;
    if (suf - h0 - h1 >= r1 && suf - h0 - h1 - h2 < r1) resB = 4 * tid + 2;
    if (suf - h0 - h1 - h2 >= r1 && suf - sv < r1) resB = 4 * tid + 3;
    __syncthreads();
    const unsigned B1 = (unsigned)resB;

    const float4* v4 = (const float4*)(lcpp + (size_t)b * NPRI);
    const int base4 = blockIdx.x * 1024;
    float4 xx[4];
    #pragma unroll
    for (int it = 0; it < 4; ++it) xx[it] = v4[base4 + it * 256 + tid];
    const float* xe = (const float*)xx;
    int myc = 0, mya = 0;
    #pragma unroll
    for (int e = 0; e < 16; ++e) {
        const unsigned bin = __float_as_uint(xe[e]) >> 21;
        myc += (bin == B1);
        mya += (bin > B1);
    }
    // packed dual block-exclusive scan (each field <= 16, block sums < 65536)
    const int pk = myc | (mya << 16);
    int inc = pk;
    #pragma unroll
    for (int d = 1; d < 64; d <<= 1) { const int t = __shfl_up(inc, d, 64); if (lane >= d) inc += t; }
    __shared__ int wt[4];
    __shared__ int sbase, sbaseA;
    if (lane == 63) wt[w] = inc;
    __syncthreads();
    int woff = 0;
    #pragma unroll
    for (int q = 0; q < 4; ++q) if (q < w) woff += wt[q];
    if (tid == 0) {
        const int tot = wt[0] + wt[1] + wt[2] + wt[3];
        sbase = atomicAdd(&cnt[b], tot & 0xFFFF);
        sbaseA = atomicAdd(&cntA[b], tot >> 16);
    }
    __syncthreads();
    const int ex = inc - pk;                              // packed exclusive within-thread base
    int pc = sbase + (woff & 0xFFFF) + (ex & 0xFFFF);
    int pa = sbaseA + (woff >> 16) + (ex >> 16);
    unsigned* cb = cand + (size_t)b * NPRI;
    #pragma unroll
    for (int e = 0; e < 16; ++e) {
        const unsigned bin = __float_as_uint(xe[e]) >> 21;
        const unsigned idx = (unsigned)(((base4 + (e >> 2) * 256 + tid) << 2) | (e & 3));
        if (bin == B1) cb[pc++] = idx;
        else if (bin > B1) cb[NPRI - 1 - pa++] = idx;
    }
}

// ---- kR3N: exact T + tie cutoff among B1-member INDICES, then (same block)
// the compacted negative-BCE + finalize. ----
__global__ __launch_bounds__(1024) void kR3N(const float* __restrict__ lcpp,
                                             const unsigned char* __restrict__ confb,
                                             const float4* __restrict__ cnf,
                                             const unsigned* __restrict__ hist,
                                             const int* __restrict__ npos,
                                             const unsigned* __restrict__ cand,
                                             const int* __restrict__ cnt,
                                             const int* __restrict__ cntA,
                                             double* __restrict__ acc,
                                             int* __restrict__ done,
                                             float* __restrict__ out) {
    const int b = blockIdx.x, tid = threadIdx.x, lane = tid & 63, w = tid >> 6;
    __shared__ unsigned h[2048];
    __shared__ unsigned wtot[16];
    __shared__ int res[2];
    __shared__ int wsum[16];
    __shared__ int srun, sIstar;
    int k = min(3 * npos[b], NPRI - 1); if (k < 1) k = 1;
    int r = k - 1;

    // level 0: precomputed 1024-bin hist
    {
        const unsigned a = hist[b * 1024 + tid];
        unsigned s = a;
        #pragma unroll
        for (int d = 1; d < 64; d <<= 1) { const unsigned t = __shfl_down(s, d, 64); if (lane + d < 64) s += t; }
        if (lane == 0) wtot[w] = s;
        __syncthreads();
        unsigned add = 0;
        #pragma unroll
        for (int q = 0; q < 16; ++q) if (q > w) add += wtot[q];
        const unsigned Sincl = s + add;
        if (Sincl >= (unsigned)(r + 1) && Sincl - a < (unsigned)(r + 1)) { res[0] = tid; res[1] = r - (int)(Sincl - a); }
        __syncthreads();
    }
    r = res[1];
    const int n = cnt[b];
    const unsigned* cd = cand + (size_t)b * NPRI;
    const float* lv = lcpp + (size_t)b * NPRI;
    __syncthreads();

    // level 1: bits[20:10] among B1 members (values gathered via indices)
    h[tid] = 0; h[tid + 1024] = 0;
    __syncthreads();
    for (int i = tid; i < n; i += 1024)
        atomicAdd(&h[(__float_as_uint(lv[cd[i]]) >> 10) & 2047u], 1u);
    __syncthreads();
    {
        const unsigned a = h[2 * tid], b2 = h[2 * tid + 1];
        const unsigned sv = a + b2;
        unsigned s = sv;
        #pragma unroll
        for (int d = 1; d < 64; d <<= 1) { const unsigned t = __shfl_down(s, d, 64); if (lane + d < 64) s += t; }
        if (lane == 0) wtot[w] = s;
        __syncthreads();
        unsigned add = 0;
        #pragma unroll
        for (int q = 0; q < 16; ++q) if (q > w) add += wtot[q];
        const unsigned Sincl = s + add;
        const unsigned r1 = (unsigned)(r + 1);
        if (Sincl >= r1 && Sincl - a < r1) { res[0] = 2 * tid; res[1] = r - (int)(Sincl - a); }
        if (Sincl - a >= r1 && Sincl - sv < r1) { res[0] = 2 * tid + 1; res[1] = r - (int)(Sincl - sv); }
        __syncthreads();
    }
    const unsigned B1 = n > 0 ? (__float_as_uint(lv[cd[0]]) >> 21) : 0u;
    const unsigned P22full = (B1 << 11) | (unsigned)res[0];
    r = res[1];
    __syncthreads();

    // level 2: bits[9:0] among P22 candidates
    h[tid] = 0;
    __syncthreads();
    for (int i = tid; i < n; i += 1024) {
        const unsigned u = __float_as_uint(lv[cd[i]]);
        if ((u >> 10) == P22full) atomicAdd(&h[u & 1023u], 1u);
    }
    __syncthreads();
    {
        const unsigned a = h[tid];
        unsigned s = a;
        #pragma unroll
        for (int d = 1; d < 64; d <<= 1) { const unsigned t = __shfl_down(s, d, 64); if (lane + d < 64) s += t; }
        if (lane == 0) wtot[w] = s;
        __syncthreads();
        unsigned add = 0;
        #pragma unroll
        for (int q = 0; q < 16; ++q) if (q > w) add += wtot[q];
        const unsigned Sincl = s + add;
        if (Sincl >= (unsigned)(r + 1) && Sincl - a < (unsigned)(r + 1)) { res[0] = tid; res[1] = r - (int)(Sincl - a); }
        __syncthreads();
    }
    const unsigned T = (P22full << 10) | (unsigned)res[0];
    const int eq = (int)h[res[0]];
    const int rem = res[1] + 1;

    int Istar = 0x7FFFFFFF;                               // all ties selected (common case)
    if (eq > rem) {                                       // rare: stable cutoff via full scan
        if (tid == 0) { srun = 0; sIstar = 0x7FFFFFFF; }
        __syncthreads();
        for (int chunk = 0; chunk < NPRI / 1024; ++chunk) {
            const int i = chunk * 1024 + tid;
            const bool tie = (__float_as_uint(lv[i]) == T);
            const unsigned long long msk = __ballot(tie);
            if (lane == 0) wsum[w] = __popcll(msk);
            __syncthreads();
            int pre = 0, tot = 0;
            #pragma unroll
            for (int q = 0; q < 16; ++q) { const int c = wsum[q]; if (q < w) pre += c; tot += c; }
            const int myrank = srun + pre + __popcll(msk & ((1ull << lane) - 1ull));
            if (tie && myrank == rem - 1) sIstar = i;
            __syncthreads();
            if (tid == 0) srun += tot;
            __syncthreads();
            if (srun >= rem) break;                       // uniform
        }
        __syncthreads();
        Istar = sIstar;
    }

    // ---- negative-BCE over compacted lists + finalize ----
    const int nA = cntA[b];
    float local = 0.0f;
    for (int i = tid; i < nA; i += 1024) {                // strictly-above: all selected
        const unsigned idx = cd[NPRI - 1 - i];
        const float4 xx = cnf[(size_t)b * NPRI + idx];
        local += bce1(xx.x, true) + bce1(xx.y, false) + bce1(xx.z, false) + bce1(xx.w, false);
    }
    for (int i = tid; i < n; i += 1024) {                 // B1 bin: tie rule
        const unsigned idx = cd[i];
        const unsigned u = __float_as_uint(lv[idx]);
        if ((u > T || (u == T && (int)idx <= Istar)) && confb[(size_t)b * NPRI + idx] == 0) {
            const float4 xx = cnf[(size_t)b * NPRI + idx];
            local += bce1(xx.x, true) + bce1(xx.y, false) + bce1(xx.z, false) + bce1(xx.w, false);
        }
    }
    #pragma unroll
    for (int s = 32; s > 0; s >>= 1) local += __shfl_down(local, s, 64);
    if (lane == 0) wtot[w] = __float_as_uint(local);
    __syncthreads();
    __shared__ bool slast;
    if (tid == 0) {
        float t = 0.0f;
        #pragma unroll
        for (int q = 0; q < 16; ++q) t += __uint_as_float(wtot[q]);
        if (t != 0.0f) atomicAdd(&acc[1], (double)t);
        __threadfence();
        const int old = atomicAdd(done, 1);
        slast = (old == BATCH - 1);
    }
    __syncthreads();
    if (slast && tid == 0) {
        __threadfence();
        int nn = 0;
        for (int q = 0; q < BATCH; ++q) nn += npos[q];
        const double a0 = atomicAdd(&acc[0], 0.0);        // atomic-RMW read: cross-XCD safe
        const double a1 = atomicAdd(&acc[1], 0.0);
        const double a2 = atomicAdd(&acc[2], 0.0);
        const double N = (double)nn;
        out[0] = (float)(a0 / N);
        out[1] = (float)(a1 / N);
        out[2] = (float)(a2 / N);
    }
}

extern "C" void kernel_launch(void* const* d_in, const int* in_sizes, int n_in,
                              void* d_out, int out_size, void* d_ws, size_t ws_size,
                              hipStream_t stream) {
    const float* loc = (const float*)d_in[0];
    const float* cnfp = (const float*)d_in[1];
    const float* regp = (const float*)d_in[2];
    const float* tgt = (const float*)d_in[3];
    const float* pri = (const float*)d_in[4];

    char* ws = (char*)d_ws;
    double* acc = (double*)(ws + OFF_ACC);
    int* done = (int*)(ws + OFF_DONE);
    int* npos = (int*)(ws + OFF_NPOS);
    int* cnt = (int*)(ws + OFF_CNT);
    int* cntA = (int*)(ws + OFF_CNTA);
    unsigned long long* bpk = (unsigned long long*)(ws + OFF_BPK);
    unsigned* hist = (unsigned*)(ws + OFF_HIST);
    unsigned char* matchb = (unsigned char*)(ws + OFF_MATCH);
    unsigned* cand = (unsigned*)(ws + OFF_CAND);
    float* lcpp = (float*)(ws + OFF_LCPP);
    float4* sp = (float4*)(ws + OFF_SP);
    unsigned* sidx = (unsigned*)(ws + OFF_SIDX);
    unsigned* cello = (unsigned*)(ws + OFF_CELLO);
    unsigned* histS = (unsigned*)(ws + OFF_HISTS);
    unsigned char* confb = (unsigned char*)(ws + OFF_CONF);

    kHist<<<16, 256, 0, stream>>>((const float4*)pri, histS);
    kScan<<<1, 256, 0, stream>>>(histS, cello, (unsigned*)ws);   // also zeroes header
    kScat<<<16, 256, 0, stream>>>((const float4*)pri, cello, sp, sidx);
    kMatch<<<dim3(16, BATCH), 256, 0, stream>>>(tgt, (const float4*)sp, sidx, bpk, matchb, hist);
    kB<<<dim3(16, BATCH), 256, 0, stream>>>(tgt, (const float4*)pri, (const float2*)loc,
                                            (const float4*)cnfp, regp, bpk, matchb,
                                            lcpp, confb, hist, acc, npos);
    kR2<<<dim3(8, BATCH), 256, 0, stream>>>(lcpp, hist, npos, cand, cnt, cntA);
    kR3N<<<BATCH, 1024, 0, stream>>>(lcpp, confb, (const float4*)cnfp, hist, npos,
                                     cand, cnt, cntA, acc, done, (float*)d_out);
}